// Round 6
// baseline (318.080 us; speedup 1.0000x reference)
//
#include <hip/hip_runtime.h>

// BoltzmannRouter: weights = renorm(top44(softmax(x @ gate_w^T / e)))
// x: (4,4096,2048) f32 ; gate_w: (64,2048) f32 ; out: (4,4096,64) f32
//
// R6 design: decoupled waves, no per-step barriers.
//  - kernel 1: pre-split gate_w -> bf16 hi/lo image in d_ws, laid out as 8
//    sub-buffers of 256 k (hi 32KB | lo 32KB each), XOR swizzle phys=l^(e&7)
//    pre-applied -> staging is a pure linear global_load_lds copy.
//  - kernel 2: grid 256 x 256thr (4 waves, 1/SIMD). Wave owns 16 tokens.
//    x: DIRECT global->VGPR A-frags (perfectly coalesced: row-quad reads
//    128B contiguous), prefetched 4 steps deep (static ring, kq unrolled).
//    w: LDS dbuf 2x64KB sub-buffers, swap every 8 k-steps (1 barrier/sub).
//    3-pass bf16 MFMA split (xhi.whi + xlo.whi + xhi.wlo), 4 indep accs.
//    Epilogue wave-local: 2-token-interleaved bitonic top-44 + f64 fixup
//    when rank-20/21 gap < GAP_EPS (proven R3-R5).

#define NTOK  16384
#define DIM   2048
#define NEXP  64
#define NACT  44
#define GAP_EPS 2e-4f

typedef __attribute__((ext_vector_type(4))) float f4;
typedef __attribute__((ext_vector_type(8))) short bf8;
typedef __attribute__((ext_vector_type(4))) float f32x4;

union BF8U { unsigned u[4]; bf8 v; };

__device__ __forceinline__ unsigned bf16rn(float f) {
  unsigned u = __float_as_uint(f);
  return (u + 0x7fffu + ((u >> 16) & 1u)) >> 16;
}

// split 8 f32 -> hi (truncated top-16 bits) + lo (bf16rn of exact residual)
__device__ __forceinline__ void split8t(f4 a, f4 b, bf8& hi, bf8& lo) {
  float fa[8] = {a.x, a.y, a.z, a.w, b.x, b.y, b.z, b.w};
  BF8U h, l;
  #pragma unroll
  for (int j = 0; j < 4; ++j) {
    const float f0 = fa[2 * j], f1 = fa[2 * j + 1];
    const unsigned u0 = __float_as_uint(f0), u1 = __float_as_uint(f1);
    const unsigned h0 = u0 & 0xffff0000u, h1 = u1 & 0xffff0000u;
    h.u[j] = (u0 >> 16) | h1;
    const float l0 = f0 - __uint_as_float(h0);   // exact
    const float l1 = f1 - __uint_as_float(h1);   // exact
    l.u[j] = bf16rn(l0) | (bf16rn(l1) << 16);
  }
  hi = h.v; lo = l.v;
}

__device__ __forceinline__ float wave_max(float v) {
  #pragma unroll
  for (int j = 32; j > 0; j >>= 1) v = fmaxf(v, __shfl_xor(v, j, 64));
  return v;
}
__device__ __forceinline__ float wave_sum(float v) {
  #pragma unroll
  for (int j = 32; j > 0; j >>= 1) v += __shfl_xor(v, j, 64);
  return v;
}

// exact f64 re-rank of one token (rare borderline path, proven R3-R5)
__device__ void fixup_token(const float* __restrict__ x,
                            const float* __restrict__ gw, int tok, int ln,
                            bool& sel, float& sv) {
  const f4* xr = reinterpret_cast<const f4*>(x + (size_t)tok * DIM);
  const f4* wr = reinterpret_cast<const f4*>(gw + (size_t)ln * DIM);
  double p0=0,p1=0,p2=0,p3=0,p4=0,p5=0,p6=0,p7=0;
  for (int k = 0; k < DIM / 8; ++k) {
    const f4 xa = xr[2*k], xb = xr[2*k+1];
    const f4 wa = wr[2*k], wb = wr[2*k+1];
    p0 = fma((double)xa.x, (double)wa.x, p0);
    p1 = fma((double)xa.y, (double)wa.y, p1);
    p2 = fma((double)xa.z, (double)wa.z, p2);
    p3 = fma((double)xa.w, (double)wa.w, p3);
    p4 = fma((double)xb.x, (double)wb.x, p4);
    p5 = fma((double)xb.y, (double)wb.y, p5);
    p6 = fma((double)xb.z, (double)wb.z, p6);
    p7 = fma((double)xb.w, (double)wb.w, p7);
  }
  const double s64 =
      (((p0+p1)+(p2+p3)) + ((p4+p5)+(p6+p7))) * 0.36787944117144233;
  double dv = s64;
  #pragma unroll
  for (int k = 2; k <= 64; k <<= 1) {
    #pragma unroll
    for (int j = k >> 1; j > 0; j >>= 1) {
      const double o = __shfl_xor(dv, j, 64);
      const bool up  = ((ln & k) == 0);
      const bool lo_ = ((ln & j) == 0);
      dv = (lo_ == up) ? fmin(dv, o) : fmax(dv, o);
    }
  }
  const double thr64 = __shfl(dv, 64 - NACT, 64);
  sel = (s64 >= thr64);
  sv = (float)s64;
}

// ---- kernel 1: pre-split w into sub-buffer LDS-image layout ---------------
// image: 8 subs x [hi: 2048 slots16B | lo: 2048 slots16B]; slot = e*32+phys,
// phys = l ^ (e&7), l = local k-slot (8 f32 -> 8 bf16).
__global__ __launch_bounds__(256) void split_w_kernel(
    const float* __restrict__ gw, unsigned short* __restrict__ img) {
  const int id  = blockIdx.x * 256 + threadIdx.x;  // 0..16383
  const int s   = id >> 11;          // sub 0..7
  const int rem = id & 2047;
  const int e   = rem >> 5;          // expert 0..63
  const int l   = rem & 31;          // local slot 0..31
  const float* src = gw + (size_t)e * DIM + s * 256 + l * 8;
  const f4 a = *reinterpret_cast<const f4*>(src);
  const f4 b = *reinterpret_cast<const f4*>(src + 4);
  bf8 hi, lo;
  split8t(a, b, hi, lo);
  const int phys = l ^ (e & 7);
  unsigned short* d = img + (size_t)s * 32768 + (e * 32 + phys) * 8;
  *reinterpret_cast<bf8*>(d)         = hi;
  *reinterpret_cast<bf8*>(d + 16384) = lo;
}

// ---- kernel 2: fused router ------------------------------------------------
__global__ __launch_bounds__(256, 1) void boltzmann_router_kernel(
    const float* __restrict__ x, const float* __restrict__ gw,
    const unsigned short* __restrict__ img, float* __restrict__ out) {
  __shared__ alignas(16) unsigned short wbuf[2][32768];  // 2 x 64 KB
  __shared__ float sc[4][16 * 65];                       // 16.6 KB

  const int t    = threadIdx.x;
  const int ln   = t & 63;
  const int wv   = t >> 6;                 // 0..3, wave-uniform
  const int tok0 = blockIdx.x * 64;

  auto STAGE = [&](int b, int sub) {
    const unsigned short* src = img + (size_t)sub * 32768;
    #pragma unroll
    for (int i = 0; i < 16; ++i) {
      const int chunk = i * 256 + wv * 64;   // wave-uniform base chunk
      __builtin_amdgcn_global_load_lds(
          (const __attribute__((address_space(1))) void*)(src + (size_t)(chunk + ln) * 8),
          (__attribute__((address_space(3))) void*)&wbuf[b][chunk * 8], 16, 0, 0);
    }
  };

  // x A-frag stream: lane row = ln&15, k-group = ln>>4 (8 consecutive f32)
  const int xrow = tok0 + wv * 16 + (ln & 15);
  const float* xb = x + (size_t)xrow * DIM + (ln >> 4) * 8;

  f4 xqa[4], xqb[4];

  STAGE(0, 0);
  __builtin_amdgcn_sched_barrier(0);
  #pragma unroll
  for (int s = 0; s < 4; ++s) {
    xqa[s] = *reinterpret_cast<const f4*>(xb + s * 32);
    xqb[s] = *reinterpret_cast<const f4*>(xb + s * 32 + 4);
  }
  asm volatile("s_waitcnt vmcnt(8)" ::: "memory");  // 16 stage loads retired
  __builtin_amdgcn_s_barrier();

  f32x4 acc[4] = {};

  #pragma unroll 1
  for (int sub = 0; sub < 8; ++sub) {
    const int cur = sub & 1;
    if (sub < 7) {
      STAGE(cur ^ 1, sub + 1);
      __builtin_amdgcn_sched_barrier(0);   // pin stage cluster before x loads
    }
    #pragma unroll
    for (int kq = 0; kq < 8; ++kq) {
      const int S = sub * 8 + kq;
      bf8 ahi, alo;
      split8t(xqa[kq & 3], xqb[kq & 3], ahi, alo);
      if (S + 4 < 64) {                    // refill ring slot (static index)
        xqa[kq & 3] = *reinterpret_cast<const f4*>(xb + (S + 4) * 32);
        xqb[kq & 3] = *reinterpret_cast<const f4*>(xb + (S + 4) * 32 + 4);
      }
      #pragma unroll
      for (int nf = 0; nf < 4; ++nf) {
        const int e    = nf * 16 + (ln & 15);
        const int phys = (kq * 4 + (ln >> 4)) ^ (e & 7);
        const int idx  = (e * 32 + phys) * 8;
        const bf8 bh = *reinterpret_cast<const bf8*>(&wbuf[cur][idx]);
        const bf8 bl = *reinterpret_cast<const bf8*>(&wbuf[cur][16384 + idx]);
        acc[nf] = __builtin_amdgcn_mfma_f32_16x16x32_bf16(ahi, bh, acc[nf], 0, 0, 0);
        acc[nf] = __builtin_amdgcn_mfma_f32_16x16x32_bf16(alo, bh, acc[nf], 0, 0, 0);
        acc[nf] = __builtin_amdgcn_mfma_f32_16x16x32_bf16(ahi, bl, acc[nf], 0, 0, 0);
      }
    }
    if (sub < 7) {
      asm volatile("s_waitcnt vmcnt(8)" ::: "memory");  // next sub staged
      __builtin_amdgcn_s_barrier();        // all waves done reading cur
    }
  }

  // ---- wave-local epilogue (no cross-wave sync needed) ----
  const float INVT = 0.36787944117144233f;  // 1/e
  #pragma unroll
  for (int nf = 0; nf < 4; ++nf) {
    #pragma unroll
    for (int r = 0; r < 4; ++r) {
      const int tr = (ln >> 4) * 4 + r;          // D row (token in strip)
      const int ec = nf * 16 + (ln & 15);        // D col (expert)
      sc[wv][tr * 65 + ec] = acc[nf][r] * INVT;
    }
  }
  // same-wave LDS write->read: compiler inserts lgkmcnt(0)

  #pragma unroll 1
  for (int it = 0; it < 8; ++it) {
    const int m0 = 2 * it, m1 = 2 * it + 1;
    const float s0 = sc[wv][m0 * 65 + ln];
    const float s1 = sc[wv][m1 * 65 + ln];

    // two interleaved bitonic sorts (independent chains hide shfl latency)
    float v0 = s0, v1 = s1;
    #pragma unroll
    for (int k = 2; k <= 64; k <<= 1) {
      #pragma unroll
      for (int j = k >> 1; j > 0; j >>= 1) {
        const float o0 = __shfl_xor(v0, j, 64);
        const float o1 = __shfl_xor(v1, j, 64);
        const bool up  = ((ln & k) == 0);
        const bool lo_ = ((ln & j) == 0);
        v0 = (lo_ == up) ? fminf(v0, o0) : fmaxf(v0, o0);
        v1 = (lo_ == up) ? fminf(v1, o1) : fmaxf(v1, o1);
      }
    }
    const float v20_0 = __shfl(v0, 64 - NACT, 64);
    const float v19_0 = __shfl(v0, 64 - NACT - 1, 64);
    const float v20_1 = __shfl(v1, 64 - NACT, 64);
    const float v19_1 = __shfl(v1, 64 - NACT - 1, 64);

    const int tokA = tok0 + wv * 16 + m0;
    const int tokB = tok0 + wv * 16 + m1;

    bool selA, selB;
    float svA = s0, svB = s1;
    if (v20_0 - v19_0 < GAP_EPS) fixup_token(x, gw, tokA, ln, selA, svA);
    else                         selA = (s0 >= v20_0);
    if (v20_1 - v19_1 < GAP_EPS) fixup_token(x, gw, tokB, ln, selB, svB);
    else                         selB = (s1 >= v20_1);

    const float mxA = wave_max(svA),            mxB = wave_max(svB);
    const float exA = __expf(svA - mxA),        exB = __expf(svB - mxB);
    const float smA = wave_sum(exA),            smB = wave_sum(exB);
    const float pA  = exA / smA,                pB  = exB / smB;
    const float psA = wave_sum(selA ? pA : 0.f), psB = wave_sum(selB ? pB : 0.f);
    out[(size_t)tokA * NEXP + ln] = selA ? (pA / (psA + 1e-8f)) : 0.0f;
    out[(size_t)tokB * NEXP + ln] = selB ? (pB / (psB + 1e-8f)) : 0.0f;
  }
}

extern "C" void kernel_launch(void* const* d_in, const int* in_sizes, int n_in,
                              void* d_out, int out_size, void* d_ws, size_t ws_size,
                              hipStream_t stream) {
  const float* x  = (const float*)d_in[0];
  const float* gw = (const float*)d_in[1];
  float* out = (float*)d_out;
  unsigned short* img = (unsigned short*)d_ws;   // 8 subs x 32768 ush = 512 KB
  split_w_kernel<<<dim3(64), dim3(256), 0, stream>>>(gw, img);
  boltzmann_router_kernel<<<dim3(NTOK / 64), dim3(256), 0, stream>>>(
      x, gw, img, out);
}